// Round 2
// baseline (52.340 us; speedup 1.0000x reference)
//
#include <hip/hip_runtime.h>
#include <hip/hip_bf16.h>

typedef unsigned short u16;
typedef __attribute__((ext_vector_type(8))) short bf16x8;
typedef __attribute__((ext_vector_type(4))) float f32x4;

#define N_ROWS 131072
#define FDIM 32
#define RDIM 256
#define ODIM 5
#define NOUT 100
#define JT 7               // ceil(100/16) output col tiles (padded to 112)
#define KST 8              // 256 / 32 k-steps for GEMM2
#define WAVES 8
#define TPW 2              // 16-row tiles per wave
#define ROWS_PER_BLOCK (WAVES * TPW * 16)   // 256
#define NBLOCKS (N_ROWS / ROWS_PER_BLOCK)   // 512

__device__ __forceinline__ u16 f2bf(float f) {
    union { float f; unsigned u; } v; v.f = f;
    return (u16)((v.u + 0x7FFFu + ((v.u >> 16) & 1u)) >> 16);  // RNE
}

// ---------------------------------------------------------------------------
// K1: M fragments in B-operand lane order for mfma_f32_16x16x32_bf16.
// mf[(rt*64+lane)*8 + e] = M[(lane>>4)*8+e][rt*16+(lane&15)]
// ---------------------------------------------------------------------------
__global__ void build_mfrag(const float* __restrict__ cs, const int* __restrict__ ci,
                            u16* __restrict__ mf) {
    int t = blockIdx.x * blockDim.x + threadIdx.x;
    if (t >= 16 * 64) return;
    int lane = t & 63;
    int rt = t >> 6;
    int r = rt * 16 + (lane & 15);
    int kbase = (lane >> 4) * 8;
#pragma unroll
    for (int e = 0; e < 8; ++e) {
        int k = kbase + e;
        float v = 0.f;
#pragma unroll
        for (int o = 0; o < ODIM; ++o)
            if (ci[r * ODIM + o] == k) v = cs[o * RDIM + r];
        mf[t * 8 + e] = f2bf(v);
    }
}

// ---------------------------------------------------------------------------
// K2: w^T fragments (B-operand of GEMM2), bf16, j padded to 112.
// wf[((jt*8+ks)*64+lane)*8 + e] = w_out[jt*16+(lane&15)][ks*32+(lane>>4)*8+e]
// ---------------------------------------------------------------------------
__global__ void build_wfrag(const float* __restrict__ w, u16* __restrict__ wf) {
    int t = blockIdx.x * blockDim.x + threadIdx.x;
    if (t >= JT * KST * 64) return;
    int lane = t & 63;
    int jt = (t >> 6) >> 3;
    int ks = (t >> 6) & 7;
    int j = jt * 16 + (lane & 15);
    int rbase = ks * 32 + (lane >> 4) * 8;
#pragma unroll
    for (int e = 0; e < 8; ++e) {
        float v = (j < NOUT) ? w[j * RDIM + rbase + e] : 0.f;
        wf[t * 8 + e] = f2bf(v);
    }
}

// ---------------------------------------------------------------------------
// Main fused kernel.
//   GEMM1: scores(16x256) = x @ M  — B1 fragments read straight from global
//          (16 KB table, L1-resident).
//   elem:  e = exp(clip(s^9,±1)); transpose to A2 layout via a 2 KB per-wave
//          LDS chunk (r in 4 chunks of 64), XOR-swizzled 16B blocks so the
//          u16 scatter stores hit all 32 banks.
//   GEMM2: out_un(16x112) = E @ w^T (wf in LDS).
//   epi:   scale by 1/rowsum, +bias, log_softmax(100), store f32.
// LDS = 57344 (wf) + 16384 (pf) = 72 KB -> 2 blocks/CU, 16 waves/CU.
// No per-tile __syncthreads: pf is wave-private, DS pipe is in-order per wave.
// ---------------------------------------------------------------------------
__global__ __launch_bounds__(WAVES * 64, 4) void hornet_main(
    const float* __restrict__ x, const u16* __restrict__ mfg,
    const u16* __restrict__ wfg, const float* __restrict__ b_out,
    float* __restrict__ out)
{
    __shared__ __align__(16) u16 wf[JT * KST * 64 * 8];   // 57344 B
    __shared__ __align__(16) u16 pf[WAVES][2 * 64 * 8];   // 16384 B (2 KB/wave)

    const int tid = threadIdx.x;
    const int wid = tid >> 6;
    const int lane = tid & 63;

    // stage wf (coalesced uint4 copies: 3584 uint4 / 512 threads = 7 each)
    {
        const uint4* wsrc = (const uint4*)wfg;
        uint4* wd = (uint4*)wf;
#pragma unroll
        for (int i = 0; i < 7; ++i) wd[tid + i * 512] = wsrc[tid + i * 512];
    }

    const int c15 = lane & 15, g = lane >> 4, ebits = c15 & 7;

    float bv[JT];
#pragma unroll
    for (int jt = 0; jt < JT; ++jt) {
        int j = jt * 16 + c15;
        bv[jt] = (j < NOUT) ? b_out[j] : 0.f;
    }
    __syncthreads();

    u16* mypf = pf[wid];

#pragma unroll 1
    for (int t = 0; t < TPW; ++t) {
        const int rowbase = blockIdx.x * ROWS_PER_BLOCK + (wid * TPW + t) * 16;

        // A1 fragment: x[rowbase+c15][g*8 + 0..7], exact in bf16
        const float* xp = x + (size_t)(rowbase + c15) * FDIM + g * 8;
        float4 xa = ((const float4*)xp)[0];
        float4 xb = ((const float4*)xp)[1];
        bf16x8 a1;
        a1[0] = (short)f2bf(xa.x); a1[1] = (short)f2bf(xa.y);
        a1[2] = (short)f2bf(xa.z); a1[3] = (short)f2bf(xa.w);
        a1[4] = (short)f2bf(xb.x); a1[5] = (short)f2bf(xb.y);
        a1[6] = (short)f2bf(xb.z); a1[7] = (short)f2bf(xb.w);

        f32x4 rs = {0.f, 0.f, 0.f, 0.f};
        bf16x8 a2[KST];

        // 4 chunks of 64 r-values: GEMM1 + elemops + swizzled transpose store,
        // then read back 2 A2 fragments. All wave-private; no barrier.
#pragma unroll
        for (int ch = 0; ch < 4; ++ch) {
#pragma unroll
            for (int q = 0; q < 4; ++q) {
                const int rt = ch * 4 + q;
                bf16x8 b1 = *((const bf16x8*)mfg + rt * 64 + lane);
                f32x4 cc = {0.f, 0.f, 0.f, 0.f};
                cc = __builtin_amdgcn_mfma_f32_16x16x32_bf16(a1, b1, cc, 0, 0, 0);
                // target 16B-block (low 6 bits; i in bits 0-1 added via XOR):
                //   blk = ksl*64 + (q&1)*32 + (c15>>3)*16 + g*4 + i
                // swizzle sw = (blk>>3)&7 (i-independent), blk' = blk ^ sw
                const int ksl = q >> 1;
                const int blk0 = ksl * 64 + (q & 1) * 32 + (c15 >> 3) * 16 + g * 4;
                const int sw = ((q & 1) * 4 + (c15 >> 3) * 2 + (g >> 1));
                const int bx = blk0 ^ sw;
#pragma unroll
                for (int i = 0; i < 4; ++i) {
                    float s = cc[i];
                    float s2 = s * s, s4 = s2 * s2, s8 = s4 * s4;
                    float p = s8 * s;                       // s^9
                    p = fminf(fmaxf(p, -1.f), 1.f);
                    float ev = __expf(p);
                    rs[i] += ev;
                    __hip_bfloat16 h = __float2bfloat16(ev);
                    mypf[((bx ^ i) * 8) + ebits] = *reinterpret_cast<u16*>(&h);
                }
            }
            // read the 2 finished A2 fragments of this chunk (same swizzle)
#pragma unroll
            for (int k2 = 0; k2 < 2; ++k2) {
                int Bp = k2 * 64 + (lane ^ ((lane >> 3) & 7));
                a2[ch * 2 + k2] = *(const bf16x8*)(mypf + Bp * 8);
            }
        }

        f32x4 acc[JT];
#pragma unroll
        for (int jt = 0; jt < JT; ++jt) acc[jt] = (f32x4){0.f, 0.f, 0.f, 0.f};
#pragma unroll
        for (int jt = 0; jt < JT; ++jt)
#pragma unroll
            for (int k = 0; k < KST; ++k) {
                bf16x8 b2 = *(const bf16x8*)(wf + ((jt * KST + k) * 64 + lane) * 8);
                acc[jt] = __builtin_amdgcn_mfma_f32_16x16x32_bf16(a2[k], b2, acc[jt], 0, 0, 0);
            }

        // full row sums of e across the 16 lanes of each group
#pragma unroll
        for (int m = 1; m <= 8; m <<= 1) {
#pragma unroll
            for (int i = 0; i < 4; ++i) rs[i] += __shfl_xor(rs[i], m, 64);
        }
        f32x4 rinv;
#pragma unroll
        for (int i = 0; i < 4; ++i) rinv[i] = 1.f / rs[i];

        // epilogue: scale, bias, log_softmax over j<100, store
#pragma unroll
        for (int i = 0; i < 4; ++i) {
            float lg[JT];
            float mx = -3.0e38f;
#pragma unroll
            for (int jt = 0; jt < JT; ++jt) {
                bool valid = (jt < 6) || (c15 < 4);
                lg[jt] = valid ? (acc[jt][i] * rinv[i] + bv[jt]) : -3.0e38f;
                mx = fmaxf(mx, lg[jt]);
            }
#pragma unroll
            for (int m = 1; m <= 8; m <<= 1) mx = fmaxf(mx, __shfl_xor(mx, m, 64));
            float se = 0.f;
#pragma unroll
            for (int jt = 0; jt < JT; ++jt) {
                bool valid = (jt < 6) || (c15 < 4);
                if (valid) se += __expf(lg[jt] - mx);
            }
#pragma unroll
            for (int m = 1; m <= 8; m <<= 1) se += __shfl_xor(se, m, 64);
            float lse = __logf(se);
            int row = rowbase + g * 4 + i;
            float* op = out + (size_t)row * NOUT;
#pragma unroll
            for (int jt = 0; jt < JT; ++jt) {
                bool valid = (jt < 6) || (c15 < 4);
                if (valid) op[jt * 16 + c15] = lg[jt] - mx - lse;
            }
        }
    }
}

extern "C" void kernel_launch(void* const* d_in, const int* in_sizes, int n_in,
                              void* d_out, int out_size, void* d_ws, size_t ws_size,
                              hipStream_t stream) {
    const float* x  = (const float*)d_in[0];
    const float* cs = (const float*)d_in[1];
    const float* w  = (const float*)d_in[2];
    const float* b  = (const float*)d_in[3];
    const int*   ci = (const int*)d_in[4];

    u16* mfg = (u16*)d_ws;             // 16 KB
    u16* wfg = mfg + 16 * 64 * 8;      // 57.3 KB

    hipLaunchKernelGGL(build_mfrag, dim3(4), dim3(256), 0, stream, cs, ci, mfg);
    hipLaunchKernelGGL(build_wfrag, dim3(14), dim3(256), 0, stream, w, wfg);
    hipLaunchKernelGGL(hornet_main, dim3(NBLOCKS), dim3(WAVES * 64), 0, stream,
                       x, mfg, wfg, b, (float*)d_out);
}

// Round 3
// 46.767 us; speedup vs baseline: 1.1192x; 1.1192x over previous
//
#include <hip/hip_runtime.h>
#include <hip/hip_bf16.h>

typedef unsigned short u16;
typedef __attribute__((ext_vector_type(8))) short bf16x8;
typedef __attribute__((ext_vector_type(4))) float f32x4;

#define N_ROWS 131072
#define FDIM 32
#define RDIM 256
#define ODIM 5
#define NOUT 100
#define JT 7               // ceil(100/16) output col tiles (padded to 112)
#define KST 8              // 256 / 32 k-steps for GEMM2
#define WAVES 8
#define TPW 2              // 16-row tiles per wave
#define ROWS_PER_BLOCK (WAVES * TPW * 16)   // 256
#define NBLOCKS (N_ROWS / ROWS_PER_BLOCK)   // 512

__device__ __forceinline__ u16 f2bf(float f) {
    union { float f; unsigned u; } v; v.f = f;
    return (u16)((v.u + 0x7FFFu + ((v.u >> 16) & 1u)) >> 16);  // RNE
}

// ---------------------------------------------------------------------------
// K1: M fragments in B-operand lane order for mfma_f32_16x16x32_bf16.
// mf[(rt*64+lane)*8 + e] = M[(lane>>4)*8+e][rt*16+(lane&15)]
// ---------------------------------------------------------------------------
__global__ void build_mfrag(const float* __restrict__ cs, const int* __restrict__ ci,
                            u16* __restrict__ mf) {
    int t = blockIdx.x * blockDim.x + threadIdx.x;
    if (t >= 16 * 64) return;
    int lane = t & 63;
    int rt = t >> 6;
    int r = rt * 16 + (lane & 15);
    int kbase = (lane >> 4) * 8;
#pragma unroll
    for (int e = 0; e < 8; ++e) {
        int k = kbase + e;
        float v = 0.f;
#pragma unroll
        for (int o = 0; o < ODIM; ++o)
            if (ci[r * ODIM + o] == k) v = cs[o * RDIM + r];
        mf[t * 8 + e] = f2bf(v);
    }
}

// ---------------------------------------------------------------------------
// K2: w^T fragments (B-operand of GEMM2), bf16, j padded to 112.
// wf[((jt*8+ks)*64+lane)*8 + e] = w_out[jt*16+(lane&15)][ks*32+(lane>>4)*8+e]
// ---------------------------------------------------------------------------
__global__ void build_wfrag(const float* __restrict__ w, u16* __restrict__ wf) {
    int t = blockIdx.x * blockDim.x + threadIdx.x;
    if (t >= JT * KST * 64) return;
    int lane = t & 63;
    int jt = (t >> 6) >> 3;
    int ks = (t >> 6) & 7;
    int j = jt * 16 + (lane & 15);
    int rbase = ks * 32 + (lane >> 4) * 8;
#pragma unroll
    for (int e = 0; e < 8; ++e) {
        float v = (j < NOUT) ? w[j * RDIM + rbase + e] : 0.f;
        wf[t * 8 + e] = f2bf(v);
    }
}

// ---------------------------------------------------------------------------
// Main fused kernel, k-outer GEMM2 fusion to keep VGPR < 128 (no spills):
// per 64-r chunk: GEMM1(4 MFMA) + pow9/exp + swizzled LDS transpose store,
// then for each of the chunk's 2 k-steps: read ONE A2 fragment and run the
// 7 jt MFMAs into acc. Only 1 a2 fragment (8 regs) live at any time.
// LDS = 57344 (wf) + 16384 (pf) = 72 KB -> 2 blocks/CU, 16 waves/CU.
// __launch_bounds__(512,2): min 2 BLOCKS/CU (CUDA semantics) -> VGPR cap 128.
// ---------------------------------------------------------------------------
__global__ __launch_bounds__(WAVES * 64, 2) void hornet_main(
    const float* __restrict__ x, const u16* __restrict__ mfg,
    const u16* __restrict__ wfg, const float* __restrict__ b_out,
    float* __restrict__ out)
{
    __shared__ __align__(16) u16 wf[JT * KST * 64 * 8];   // 57344 B
    __shared__ __align__(16) u16 pf[WAVES][2 * 64 * 8];   // 16384 B (2 KB/wave)

    const int tid = threadIdx.x;
    const int wid = tid >> 6;
    const int lane = tid & 63;

    // stage wf (coalesced uint4 copies: 3584 uint4 / 512 threads = 7 each)
    {
        const uint4* wsrc = (const uint4*)wfg;
        uint4* wd = (uint4*)wf;
#pragma unroll
        for (int i = 0; i < 7; ++i) wd[tid + i * 512] = wsrc[tid + i * 512];
    }

    const int c15 = lane & 15, g = lane >> 4, ebits = c15 & 7;
    __syncthreads();

    u16* mypf = pf[wid];

#pragma unroll 1
    for (int t = 0; t < TPW; ++t) {
        const int rowbase = blockIdx.x * ROWS_PER_BLOCK + (wid * TPW + t) * 16;

        // A1 fragment: x[rowbase+c15][g*8 + 0..7], exact in bf16
        const float* xp = x + (size_t)(rowbase + c15) * FDIM + g * 8;
        float4 xa = ((const float4*)xp)[0];
        float4 xb = ((const float4*)xp)[1];
        bf16x8 a1;
        a1[0] = (short)f2bf(xa.x); a1[1] = (short)f2bf(xa.y);
        a1[2] = (short)f2bf(xa.z); a1[3] = (short)f2bf(xa.w);
        a1[4] = (short)f2bf(xb.x); a1[5] = (short)f2bf(xb.y);
        a1[6] = (short)f2bf(xb.z); a1[7] = (short)f2bf(xb.w);

        f32x4 rs = {0.f, 0.f, 0.f, 0.f};
        f32x4 acc[JT];
#pragma unroll
        for (int jt = 0; jt < JT; ++jt) acc[jt] = (f32x4){0.f, 0.f, 0.f, 0.f};

        // 4 chunks of 64 r-values: GEMM1 + elemops + swizzled transpose store,
        // then immediately consume the chunk's 2 A2 fragments in GEMM2.
#pragma unroll
        for (int ch = 0; ch < 4; ++ch) {
#pragma unroll
            for (int q = 0; q < 4; ++q) {
                const int rt = ch * 4 + q;
                bf16x8 b1 = *((const bf16x8*)mfg + rt * 64 + lane);
                f32x4 cc = {0.f, 0.f, 0.f, 0.f};
                cc = __builtin_amdgcn_mfma_f32_16x16x32_bf16(a1, b1, cc, 0, 0, 0);
                // target 16B-block: blk = ksl*64 + (q&1)*32 + (c15>>3)*16 + g*4 + i
                // swizzle sw = (blk>>3)&7 (i-independent), blk' = blk ^ sw
                const int ksl = q >> 1;
                const int blk0 = ksl * 64 + (q & 1) * 32 + (c15 >> 3) * 16 + g * 4;
                const int sw = ((q & 1) * 4 + (c15 >> 3) * 2 + (g >> 1));
                const int bx = blk0 ^ sw;
#pragma unroll
                for (int i = 0; i < 4; ++i) {
                    float s = cc[i];
                    float s2 = s * s, s4 = s2 * s2, s8 = s4 * s4;
                    float p = s8 * s;                       // s^9
                    p = fminf(fmaxf(p, -1.f), 1.f);
                    float ev = __expf(p);
                    rs[i] += ev;
                    __hip_bfloat16 h = __float2bfloat16(ev);
                    mypf[((bx ^ i) * 8) + ebits] = *reinterpret_cast<u16*>(&h);
                }
            }
            // consume this chunk's 2 A2 fragments (same swizzle on read)
#pragma unroll
            for (int k2 = 0; k2 < 2; ++k2) {
                const int k = ch * 2 + k2;
                const int Bp = k2 * 64 + (lane ^ ((lane >> 3) & 7));
                bf16x8 a2 = *(const bf16x8*)(mypf + Bp * 8);
#pragma unroll
                for (int jt = 0; jt < JT; ++jt) {
                    bf16x8 b2 = *(const bf16x8*)(wf + ((jt * KST + k) * 64 + lane) * 8);
                    acc[jt] = __builtin_amdgcn_mfma_f32_16x16x32_bf16(a2, b2, acc[jt], 0, 0, 0);
                }
            }
        }

        // full row sums of e across the 16 lanes of each group
#pragma unroll
        for (int m = 1; m <= 8; m <<= 1) {
#pragma unroll
            for (int i = 0; i < 4; ++i) rs[i] += __shfl_xor(rs[i], m, 64);
        }
        f32x4 rinv;
#pragma unroll
        for (int i = 0; i < 4; ++i) rinv[i] = 1.f / rs[i];

        // epilogue: scale, bias, log_softmax over j<100, store
        float bv[JT];
#pragma unroll
        for (int jt = 0; jt < JT; ++jt) {
            int j = jt * 16 + c15;
            bv[jt] = (j < NOUT) ? b_out[j] : 0.f;
        }
#pragma unroll
        for (int i = 0; i < 4; ++i) {
            float lg[JT];
            float mx = -3.0e38f;
#pragma unroll
            for (int jt = 0; jt < JT; ++jt) {
                bool valid = (jt < 6) || (c15 < 4);
                lg[jt] = valid ? (acc[jt][i] * rinv[i] + bv[jt]) : -3.0e38f;
                mx = fmaxf(mx, lg[jt]);
            }
#pragma unroll
            for (int m = 1; m <= 8; m <<= 1) mx = fmaxf(mx, __shfl_xor(mx, m, 64));
            float se = 0.f;
#pragma unroll
            for (int jt = 0; jt < JT; ++jt) {
                bool valid = (jt < 6) || (c15 < 4);
                if (valid) se += __expf(lg[jt] - mx);
            }
#pragma unroll
            for (int m = 1; m <= 8; m <<= 1) se += __shfl_xor(se, m, 64);
            float lse = __logf(se);
            int row = rowbase + g * 4 + i;
            float* op = out + (size_t)row * NOUT;
#pragma unroll
            for (int jt = 0; jt < JT; ++jt) {
                bool valid = (jt < 6) || (c15 < 4);
                if (valid) op[jt * 16 + c15] = lg[jt] - mx - lse;
            }
        }
    }
}

extern "C" void kernel_launch(void* const* d_in, const int* in_sizes, int n_in,
                              void* d_out, int out_size, void* d_ws, size_t ws_size,
                              hipStream_t stream) {
    const float* x  = (const float*)d_in[0];
    const float* cs = (const float*)d_in[1];
    const float* w  = (const float*)d_in[2];
    const float* b  = (const float*)d_in[3];
    const int*   ci = (const int*)d_in[4];

    u16* mfg = (u16*)d_ws;             // 16 KB
    u16* wfg = mfg + 16 * 64 * 8;      // 57.3 KB

    hipLaunchKernelGGL(build_mfrag, dim3(4), dim3(256), 0, stream, cs, ci, mfg);
    hipLaunchKernelGGL(build_wfrag, dim3(14), dim3(256), 0, stream, w, wfg);
    hipLaunchKernelGGL(hornet_main, dim3(NBLOCKS), dim3(WAVES * 64), 0, stream,
                       x, mfg, wfg, b, (float*)d_out);
}